// Round 1
// baseline (4118.019 us; speedup 1.0000x reference)
//
#include <hip/hip_runtime.h>

typedef unsigned short u16;
typedef unsigned int   u32;
typedef unsigned long long u64;
typedef __attribute__((ext_vector_type(8))) short short8v;
typedef __attribute__((ext_vector_type(4))) float f32x4;

#define DINL __device__ __forceinline__

DINL u16 f2bf(float f){ union{float f;u32 u;} v{f}; return (u16)((v.u + 0x7fffu + ((v.u>>16)&1u))>>16); }
DINL float bf2f(u16 b){ union{u32 u;float f;} v{(u32)b<<16}; return v.f; }
DINL f32x4 MFMA16(short8v a, short8v b, f32x4 c){ return __builtin_amdgcn_mfma_f32_16x16x32_bf16(a,b,c,0,0,0); }
DINL void gl16(const void* g, void* l){
  __builtin_amdgcn_global_load_lds((const __attribute__((address_space(1))) void*)g,
                                   (__attribute__((address_space(3))) void*)l, 16, 0, 0);
}
DINL float wredd(float v){
#pragma unroll
  for (int m=1;m<64;m<<=1) v += __shfl_xor(v, m);
  return v;
}
DINL float sigm(float x){ return 1.f/(1.f+__expf(-x)); }
DINL float tanh_(float x){ return 2.f/(1.f+__expf(-2.f*x)) - 1.f; }

// ---------------- generic fp32 -> bf16 convert ----------------
__global__ __launch_bounds__(256) void cvtk(const float* __restrict__ src, u16* __restrict__ dst, int n){
  int i = (blockIdx.x*256 + threadIdx.x)*4;
  float4 v = *(const float4*)(src + i);
  dst[i+0]=f2bf(v.x); dst[i+1]=f2bf(v.y); dst[i+2]=f2bf(v.z); dst[i+3]=f2bf(v.w);
}

// ---------------- 128x128 bf16 MFMA GEMM, m97 structure ----------------
// C[M,N] = A[M,K] @ W[N,K]^T  (+ per-EPI epilogue)
// EPI 0: in-proj: +bias0[n] + sinusoidal PE(t=m&1023,n) -> bf16 out[m*512+n]
// EPI 1: fused QKV (N=1536): g=n>>9 picks q/k/v; q,k -> [bh][t][64]; v -> [bh][64][1024] (transposed)
// EPI 3: o-proj: +bias0[n] + residual bf16 -> bf16 out[m*512+n]
template<int EPI>
__global__ __launch_bounds__(256) void gemm128(
    const u16* __restrict__ A, const u16* __restrict__ W,
    const float* __restrict__ bias0, const float* __restrict__ bias1, const float* __restrict__ bias2,
    const u16* __restrict__ resid, u16* __restrict__ out, int M, int N, int K)
{
  __shared__ __align__(16) u16 Al[128*64];
  __shared__ __align__(16) u16 Bl[128*64];
  const int tid = threadIdx.x, lane = tid & 63, w = tid >> 6;
  const int wr = w >> 1, wc = w & 1;
  const int m0 = blockIdx.y * 128, n0 = blockIdx.x * 128;
  f32x4 acc[4][4] = {};
  for (int k0 = 0; k0 < K; k0 += 64) {
#pragma unroll
    for (int j = 0; j < 4; ++j) {
      int idx = (j*4 + w)*64 + lane;
      int r = idx >> 3, c8 = idx & 7;
      gl16(A + (size_t)(m0 + r)*K + k0 + c8*8, (void*)(Al + (size_t)(j*4+w)*512));
      gl16(W + (size_t)(n0 + r)*K + k0 + c8*8, (void*)(Bl + (size_t)(j*4+w)*512));
    }
    __syncthreads();
#pragma unroll
    for (int kk = 0; kk < 2; ++kk) {
      short8v af[4], bf[4];
#pragma unroll
      for (int i = 0; i < 4; ++i)
        af[i] = *(const short8v*)(Al + ((wr*64 + i*16 + (lane&15))*64 + kk*32 + (lane>>4)*8));
#pragma unroll
      for (int i = 0; i < 4; ++i)
        bf[i] = *(const short8v*)(Bl + ((wc*64 + i*16 + (lane&15))*64 + kk*32 + (lane>>4)*8));
#pragma unroll
      for (int mi=0;mi<4;++mi)
#pragma unroll
        for (int ni=0;ni<4;++ni)
          acc[mi][ni] = MFMA16(af[mi], bf[ni], acc[mi][ni]);
    }
    __syncthreads();
  }
  // epilogue: C row = m0+wr*64+mi*16+(lane>>4)*4+r ; col = n0+wc*64+ni*16+(lane&15)
#pragma unroll
  for (int mi=0;mi<4;++mi)
#pragma unroll
    for (int ni=0;ni<4;++ni)
#pragma unroll
      for (int r=0;r<4;++r) {
        int m = m0 + wr*64 + mi*16 + (lane>>4)*4 + r;
        int n = n0 + wc*64 + ni*16 + (lane&15);
        float v = acc[mi][ni][r];
        if constexpr (EPI == 0) {
          int t = m & 1023;
          float ang = (float)t * expf((float)(n & ~1) * (-9.210340371976184f/512.f));
          v += bias0[n] + ((n & 1) ? cosf(ang) : sinf(ang));
          out[(size_t)m*512 + n] = f2bf(v);
        } else if constexpr (EPI == 1) {
          int g = n >> 9, n5 = n & 511, hh = n5 >> 6, dh = n5 & 63;
          v += (g==0 ? bias0 : g==1 ? bias1 : bias2)[n5];
          size_t bh = (size_t)((m>>10)*8 + hh);
          u16 val = f2bf(v);
          if (g == 0)      out[(bh*1024 + (m&1023))*64 + dh] = val;
          else if (g == 1) out[4194304 + (bh*1024 + (m&1023))*64 + dh] = val;
          else             out[8388608 + (bh*64 + dh)*1024 + (m&1023)] = val;
        } else {
          v += bias0[n] + bf2f(resid[(size_t)m*512 + n]);
          out[(size_t)m*512 + n] = f2bf(v);
        }
      }
}

// ---------------- causal flash attention: 1 WG per (b,h, 64 q-rows) ----------------
__global__ __launch_bounds__(256) void attnk(const u16* __restrict__ qb, const u16* __restrict__ kb,
                                             const u16* __restrict__ vt, u16* __restrict__ attno)
{
  __shared__ __align__(16) u16 P[4][16][72];   // per-wave P tile, padded row stride 144B
  const int tid = threadIdx.x, lane = tid & 63, w = tid >> 6;
  const int bh = blockIdx.x >> 4, qblk = blockIdx.x & 15;
  const int b = bh >> 3, h = bh & 7;
  const float scale = 0.125f;
  short8v qf[2];
  {
    const u16* qbase = qb + ((size_t)bh*1024 + qblk*64 + w*16)*64;
#pragma unroll
    for (int kk=0;kk<2;++kk)
      qf[kk] = *(const short8v*)(qbase + (size_t)(lane&15)*64 + kk*32 + (lane>>4)*8);
  }
  f32x4 o[4] = {};
  float mrun[4], lrun[4];
#pragma unroll
  for (int r=0;r<4;++r){ mrun[r] = -1e30f; lrun[r] = 0.f; }
  for (int kblk = 0; kblk <= qblk; ++kblk) {
    f32x4 s[4] = {};
#pragma unroll
    for (int kk=0;kk<2;++kk)
#pragma unroll
      for (int nt=0;nt<4;++nt) {
        short8v kf = *(const short8v*)(kb + ((size_t)bh*1024 + kblk*64 + nt*16 + (lane&15))*64 + kk*32 + (lane>>4)*8);
        s[nt] = MFMA16(qf[kk], kf, s[nt]);
      }
    float pnew[4][4];
#pragma unroll
    for (int r=0;r<4;++r) {
      int q = qblk*64 + w*16 + (lane>>4)*4 + r;
      float sv[4]; float rowmax = -1e30f;
#pragma unroll
      for (int nt=0;nt<4;++nt) {
        int key = kblk*64 + nt*16 + (lane&15);
        float x = s[nt][r]*scale;
        if (key > q) x = -1e30f;
        sv[nt] = x; rowmax = fmaxf(rowmax, x);
      }
#pragma unroll
      for (int msk=1; msk<16; msk<<=1) rowmax = fmaxf(rowmax, __shfl_xor(rowmax, msk));
      float mnew = fmaxf(mrun[r], rowmax);
      float sf = __expf(mrun[r]-mnew);
      float psum = 0.f;
#pragma unroll
      for (int nt=0;nt<4;++nt){ float p = __expf(sv[nt]-mnew); pnew[nt][r]=p; psum += p; }
#pragma unroll
      for (int msk=1; msk<16; msk<<=1) psum += __shfl_xor(psum, msk);
      lrun[r] = lrun[r]*sf + psum;
      mrun[r] = mnew;
#pragma unroll
      for (int nt=0;nt<4;++nt) o[nt][r] *= sf;
    }
#pragma unroll
    for (int nt=0;nt<4;++nt)
#pragma unroll
      for (int r=0;r<4;++r)
        P[w][(lane>>4)*4+r][nt*16+(lane&15)] = f2bf(pnew[nt][r]);
#pragma unroll
    for (int kk=0;kk<2;++kk) {
      short8v pf = *(const short8v*)&P[w][lane&15][kk*32 + (lane>>4)*8];
#pragma unroll
      for (int nt=0;nt<4;++nt) {
        short8v vf = *(const short8v*)(vt + ((size_t)bh*64 + nt*16 + (lane&15))*1024 + kblk*64 + kk*32 + (lane>>4)*8);
        o[nt] = MFMA16(pf, vf, o[nt]);
      }
    }
  }
#pragma unroll
  for (int nt=0;nt<4;++nt)
#pragma unroll
    for (int r=0;r<4;++r) {
      int q = qblk*64 + w*16 + (lane>>4)*4 + r;
      int dh = nt*16 + (lane&15);
      attno[((size_t)b*1024 + q)*512 + h*64 + dh] = f2bf(o[nt][r] / lrun[r]);
    }
}

// ---------------- LayerNorm 1 (rows of 512), write x_lstm [t][b][512] bf16 ----------------
__global__ __launch_bounds__(256) void ln1k(const u16* __restrict__ pre, const float* __restrict__ g1,
                                            const float* __restrict__ b1, u16* __restrict__ xl){
  int row = blockIdx.x*4 + (threadIdx.x>>6), lane = threadIdx.x&63;
  short8v xv = *(const short8v*)(pre + (size_t)row*512 + lane*8);
  float v[8], s=0.f, s2=0.f;
#pragma unroll
  for (int e=0;e<8;++e){ v[e]=bf2f((u16)xv[e]); s+=v[e]; s2+=v[e]*v[e]; }
  s = wredd(s); s2 = wredd(s2);
  float mu = s*(1.f/512.f);
  float rs = rsqrtf(s2*(1.f/512.f) - mu*mu + 1e-5f);
  int b = row>>10, t = row&1023;
  short8v ov;
#pragma unroll
  for (int e=0;e<8;++e){ int c=lane*8+e; ov[e]=(short)f2bf((v[e]-mu)*rs*g1[c]+b1[c]); }
  *(short8v*)(xl + ((size_t)t*8 + b)*512 + lane*8) = ov;
}

// ---------------- persistent bidirectional LSTM ----------------
// 64 WGs: d = blk>>5 (0 fwd, 1 bwd), slice = blk&31 owns 16 units (cols of all 4 gates).
// wih/whh slice pre-packed as MFMA B-fragments in LDS. c-state in registers.
// h exchanged via write-through agent atomics + per-WG release flags.
__global__ __launch_bounds__(256) void lstmk(
    const u16* __restrict__ xl,
    const float* __restrict__ wih_f, const float* __restrict__ whh_f,
    const float* __restrict__ bih_f, const float* __restrict__ bhh_f,
    const float* __restrict__ wih_b, const float* __restrict__ whh_b,
    const float* __restrict__ bih_b, const float* __restrict__ bhh_b,
    u16* __restrict__ hc, u32* __restrict__ flg)
{
  extern __shared__ char smem[];
  u16*  WI  = (u16*)smem;               // 64 KB: [4nt][16kc][64lane][8]
  u16*  WH  = (u16*)(smem + 65536);     // 64 KB
  float* RED = (float*)(smem + 131072); // 8 KB: [4w][4nt][32lane][4reg]
  u16*  HST = (u16*)(smem + 139264);    // 256 B: [8b][16u]

  const int tid = threadIdx.x, lane = tid&63, w = tid>>6;
  const int d = blockIdx.x >> 5, slice = blockIdx.x & 31, u0 = slice*16;
  const float* WIHg = d ? wih_b : wih_f;
  const float* WHHg = d ? whh_b : whh_f;
  const float* BIH  = d ? bih_b : bih_f;
  const float* BHH  = d ? bhh_b : bhh_f;

  // fill weight fragments (gate nt, k-chunk kc, lane l) -> 8 contiguous-K bf16
  for (int f = tid; f < 4096; f += 256) {
    int nt = f>>10, kc = (f>>6)&15, l = f&63;
    size_t grow = (size_t)(nt*512 + u0 + (l&15));
    int k = kc*32 + (l>>4)*8;
    const float* pi = WIHg + grow*512 + k;
    const float* ph = WHHg + grow*512 + k;
    short8v wa, wb;
#pragma unroll
    for (int e=0;e<8;++e){ wa[e]=(short)f2bf(pi[e]); wb[e]=(short)f2bf(ph[e]); }
    *(short8v*)(WI + (size_t)f*8) = wa;
    *(short8v*)(WH + (size_t)f*8) = wb;
  }
  __syncthreads();

  const bool act = tid < 128;
  const int b_ = tid>>4, u_ = tid&15;
  float c_state = 0.f, bias_c[4];
  if (act)
#pragma unroll
    for (int g=0;g<4;++g) bias_c[g] = BIH[g*512+u0+u_] + BHH[g*512+u0+u_];

  for (int t = 0; t < 1024; ++t) {
    int te = d ? 1023 - t : t;
    f32x4 acc[4] = {};
    { // x @ wih^T  (independent of h -> before the wait)
      const u16* xb = xl + ((size_t)te*8 + (lane&7))*512;
#pragma unroll
      for (int kk=0;kk<4;++kk) {
        int kc = w*4 + kk;
        short8v xf = *(const short8v*)(xb + kc*32 + (lane>>4)*8);
#pragma unroll
        for (int nt=0;nt<4;++nt)
          acc[nt] = MFMA16(xf, *(const short8v*)(WI + ((size_t)(nt*16+kc)*64 + lane)*8), acc[nt]);
      }
    }
    if (t > 0) {
      if (w == 0) {
        const u32* fb = flg + ((size_t)d*1024 + (t-1))*32;
        u64 pend;
        do {
          u32 ok = (lane < 32) ? __hip_atomic_load(fb + lane, __ATOMIC_ACQUIRE, __HIP_MEMORY_SCOPE_AGENT) : 1u;
          pend = __ballot(ok == 0u);
          if (pend) __builtin_amdgcn_s_sleep(1);
        } while (pend);
      }
      __syncthreads();
      int tp = d ? 1024 - t : t - 1;           // h_comm slot of previous state
      const u16* hb = hc + ((size_t)d*1024 + tp)*4096 + (size_t)(lane&7)*512;
#pragma unroll
      for (int kk=0;kk<4;++kk) {
        int kc = w*4 + kk;
        short8v hf = *(const short8v*)(hb + kc*32 + (lane>>4)*8);
#pragma unroll
        for (int nt=0;nt<4;++nt)
          acc[nt] = MFMA16(hf, *(const short8v*)(WH + ((size_t)(nt*16+kc)*64 + lane)*8), acc[nt]);
      }
    }
    if (lane < 32)
#pragma unroll
      for (int nt=0;nt<4;++nt)
        *(f32x4*)(RED + ((size_t)(w*4+nt)*32 + lane)*4) = acc[nt];
    __syncthreads();
    if (act) {
      int lc = u_ + 16*(b_>>2), rg = b_&3;
      float gates[4];
#pragma unroll
      for (int g=0;g<4;++g) {
        float s = 0.f;
#pragma unroll
        for (int wv=0;wv<4;++wv) s += RED[((size_t)(wv*4+g)*32 + lc)*4 + rg];
        gates[g] = s + bias_c[g];
      }
      float ig = sigm(gates[0]), fg = sigm(gates[1]), gg = tanh_(gates[2]), og = sigm(gates[3]);
      c_state = fg*c_state + ig*gg;
      HST[b_*16 + u_] = f2bf(og * tanh_(c_state));
    }
    __syncthreads();
    if (tid < 32) {
      int b2 = tid>>2, q = tid&3;
      u64 v = *(const u64*)(HST + b2*16 + q*4);
      u64* dst = (u64*)(hc + ((size_t)d*1024 + te)*4096 + (size_t)b2*512 + u0 + q*4);
      __hip_atomic_store(dst, v, __ATOMIC_RELAXED, __HIP_MEMORY_SCOPE_AGENT);
    }
    __syncthreads();                           // drains each wave's vmcnt -> stores visible
    if (tid == 0)
      __hip_atomic_store(flg + ((size_t)d*1024 + t)*32 + slice, 1u, __ATOMIC_RELEASE, __HIP_MEMORY_SCOPE_AGENT);
  }
}

// ---------------- LayerNorm 2 (rows of 1024 = concat fwd/bwd) + time-mean accumulate ----------------
__global__ __launch_bounds__(256) void ln2k(const u16* __restrict__ hc, const float* __restrict__ g2,
                                            const float* __restrict__ b2, float* __restrict__ emb){
  __shared__ float accl[4][1024];
  int b = blockIdx.x>>4, chunk = blockIdx.x&15;
  int lane = threadIdx.x&63, w = threadIdx.x>>6;
  for (int i=lane;i<1024;i+=64) accl[w][i]=0.f;
#pragma unroll 1
  for (int i=0;i<16;++i) {
    int t = chunk*64 + w*16 + i;
    short8v xf = *(const short8v*)(hc + ((size_t)t*8 + b)*512 + lane*8);
    short8v xb = *(const short8v*)(hc + ((size_t)(1024+t)*8 + b)*512 + lane*8);
    float vf[8], vb[8], s=0.f, s2=0.f;
#pragma unroll
    for (int e=0;e<8;++e){ vf[e]=bf2f((u16)xf[e]); vb[e]=bf2f((u16)xb[e]);
                           s += vf[e]+vb[e]; s2 += vf[e]*vf[e]+vb[e]*vb[e]; }
    s = wredd(s); s2 = wredd(s2);
    float mu = s*(1.f/1024.f);
    float rs = rsqrtf(s2*(1.f/1024.f) - mu*mu + 1e-5f);
#pragma unroll
    for (int e=0;e<8;++e){
      int c = lane*8+e;
      accl[w][c]     += (vf[e]-mu)*rs*g2[c]     + b2[c];
      accl[w][512+c] += (vb[e]-mu)*rs*g2[512+c] + b2[512+c];
    }
  }
  __syncthreads();
  for (int c = threadIdx.x; c < 1024; c += 256)
    atomicAdd(emb + (size_t)b*1024 + c, accl[0][c]+accl[1][c]+accl[2][c]+accl[3][c]);
}

// ---------------- final: out[b][n] = b_out[n] + (embsum[b]/1024) . w_out[n] ----------------
__global__ __launch_bounds__(256) void fink(const float* __restrict__ emb, const float* __restrict__ w_out,
                                            const float* __restrict__ b_out, float* __restrict__ out){
  int gid = blockIdx.x*256 + threadIdx.x;
  int n = gid>>3, b = gid&7;
  const float* e = emb + (size_t)b*1024;
  const float* wr = w_out + (size_t)n*1024;
  float s = 0.f;
  for (int k=0;k<1024;k+=4) {
    float4 ev = *(const float4*)(e+k);
    float4 wv = *(const float4*)(wr+k);
    s += ev.x*wv.x + ev.y*wv.y + ev.z*wv.z + ev.w*wv.w;
  }
  out[(size_t)b*512 + n] = b_out[n] + s*(1.f/1024.f);
}

// ---------------- workspace layout (bytes) ----------------
#define OFF_FLG   0u          // [2][1024][32] u32 = 262144   (memset 0 each launch)
#define OFF_EMB   262144u     // [8][1024] f32 = 32768        (memset 0 each launch)
#define OFF_A0    327680u     // [8192][256] bf16 = 4194304
#define OFF_WIN   4521984u    // [512][256] bf16 = 262144
#define OFF_WQKV  4784128u    // [1536][512] bf16 = 1572864
#define OFF_WO    6356992u    // [512][512] bf16 = 524288
#define OFF_X0B   6881280u    // [8192][512] bf16 = 8388608
#define OFF_QB    15269888u   // q+k+v bf16 = 3*8388608
#define OFF_ATT   40435712u   // [8192][512] bf16 = 8388608
#define OFF_PRE   48824320u   // [8192][512] bf16 = 8388608
#define OFF_XL    57212928u   // [1024][8][512] bf16 = 8388608
#define OFF_HC    65601536u   // [2][1024][8][512] bf16 = 16777216  (doubles as hs output)

extern "C" void kernel_launch(void* const* d_in, const int* in_sizes, int n_in,
                              void* d_out, int out_size, void* d_ws, size_t ws_size,
                              hipStream_t stream) {
  const float* temporal = (const float*)d_in[0];
  const float* w_in = (const float*)d_in[1];  const float* b_in = (const float*)d_in[2];
  const float* wq = (const float*)d_in[3];    const float* bq = (const float*)d_in[4];
  const float* wk = (const float*)d_in[5];    const float* bk = (const float*)d_in[6];
  const float* wv = (const float*)d_in[7];    const float* bv = (const float*)d_in[8];
  const float* wo = (const float*)d_in[9];    const float* bo = (const float*)d_in[10];
  const float* g1 = (const float*)d_in[11];   const float* b1 = (const float*)d_in[12];
  const float* wih_f = (const float*)d_in[13]; const float* whh_f = (const float*)d_in[14];
  const float* bih_f = (const float*)d_in[15]; const float* bhh_f = (const float*)d_in[16];
  const float* wih_b = (const float*)d_in[17]; const float* whh_b = (const float*)d_in[18];
  const float* bih_b = (const float*)d_in[19]; const float* bhh_b = (const float*)d_in[20];
  const float* g2 = (const float*)d_in[21];   const float* b2 = (const float*)d_in[22];
  const float* w_out = (const float*)d_in[23]; const float* b_out = (const float*)d_in[24];

  char* ws = (char*)d_ws;
  u32* FLG = (u32*)(ws + OFF_FLG);
  float* EMB = (float*)(ws + OFF_EMB);
  u16* A0   = (u16*)(ws + OFF_A0);
  u16* WIN  = (u16*)(ws + OFF_WIN);
  u16* WQKV = (u16*)(ws + OFF_WQKV);
  u16* WOb  = (u16*)(ws + OFF_WO);
  u16* X0B  = (u16*)(ws + OFF_X0B);
  u16* QB   = (u16*)(ws + OFF_QB);
  u16* ATT  = (u16*)(ws + OFF_ATT);
  u16* PRE  = (u16*)(ws + OFF_PRE);
  u16* XL   = (u16*)(ws + OFF_XL);
  u16* HC   = (u16*)(ws + OFF_HC);

  (void)hipFuncSetAttribute((const void*)lstmk, hipFuncAttributeMaxDynamicSharedMemorySize, 139520);

  hipMemsetAsync(ws, 0, 294912, stream);  // flags + embsum

  cvtk<<<2048,256,0,stream>>>(temporal, A0, 2097152);
  cvtk<<<128, 256,0,stream>>>(w_in, WIN, 131072);
  cvtk<<<256, 256,0,stream>>>(wq, WQKV,           262144);
  cvtk<<<256, 256,0,stream>>>(wk, WQKV + 262144,  262144);
  cvtk<<<256, 256,0,stream>>>(wv, WQKV + 524288,  262144);
  cvtk<<<256, 256,0,stream>>>(wo, WOb, 262144);

  gemm128<0><<<dim3(4,64), 256, 0, stream>>>(A0, WIN, b_in, nullptr, nullptr, nullptr, X0B, 8192, 512, 256);
  gemm128<1><<<dim3(12,64),256, 0, stream>>>(X0B, WQKV, bq, bk, bv, nullptr, QB, 8192, 1536, 512);
  attnk<<<1024,256,0,stream>>>(QB, QB + 4194304, QB + 8388608, ATT);
  gemm128<3><<<dim3(4,64), 256, 0, stream>>>(ATT, WOb, bo, nullptr, nullptr, X0B, PRE, 8192, 512, 512);
  ln1k<<<2048,256,0,stream>>>(PRE, g1, b1, XL);
  lstmk<<<64,256,139520,stream>>>(XL, wih_f, whh_f, bih_f, bhh_f, wih_b, whh_b, bih_b, bhh_b, HC, FLG);
  ln2k<<<128,256,0,stream>>>(HC, g2, b2, EMB);
  fink<<<16,256,0,stream>>>(EMB, w_out, b_out, (float*)d_out);
}